// Round 1
// 167.054 us; speedup vs baseline: 1.0053x; 1.0053x over previous
//
#include <hip/hip_runtime.h>

#define BB 16
#define LL 2048
#define DD 768
#define KK 32
#define NEGI -1e30f
#define JJ 8                 // sub-blocks per span (split-J)
#define AW 4                 // waves per A-block
#define SLOTS (JJ * AW)      // 32 row-slots per span

// Phase A: grid (B*K, J). Each block = 4 waves; wave handles rows
// l = s0 + (j*AW + wave) + i*32 of span bk. Online-softmax state in
// registers (identical row body to the previous single-kernel version),
// 4-wave LDS merge, then ONE unnormalized partial (m, s, acc[768]) per
// (bk, j) to workspace. Splitting the span 8 ways kills the makespan
// tail: the longest span (~300 rows) was one block on one CU (~0.9 MB
// streamed alone ≈ 40 µs); now it is 8 blocks of ~114 KB each, and the
// 4096-block grid gives the scheduler a rebalancing pool (~16 blocks/CU
// queued vs exactly 2 before). No cross-workgroup sync anywhere.
__global__ __launch_bounds__(256) void span_pool_a(
    const float* __restrict__ th,
    const float* __restrict__ attn,
    const int* __restrict__ sps,
    const int* __restrict__ spe,
    const float* __restrict__ wp,
    float* __restrict__ pacc,   // [B*K, J, 768] unnormalized
    float* __restrict__ pm,     // [B*K, J] running max
    float* __restrict__ ps) {   // [B*K, J] running sum
  const int bk = blockIdx.x;          // b*K + k
  const int j  = blockIdx.y;          // sub-block within span
  const int b  = bk >> 5;             // K = 32
  const int lane = threadIdx.x & 63;
  const int wave = threadIdx.x >> 6;
  const int slot = j * AW + wave;     // 0..31

  __shared__ float sacc[AW][DD];      // 12 KB wave-partial accumulators
  __shared__ float sm[AW], ss[AW];

  int s0 = min(max(sps[bk], 0), LL);
  int e0 = min(max(spe[bk], 0), LL);

  // pooling weights: lane owns dims {4*lane, 256+4*lane, 512+4*lane}+[0,3]
  const float4* wr = (const float4*)wp;
  const float4 w0 = wr[lane], w1 = wr[lane + 64], w2 = wr[lane + 128];

  const float* arow = attn + (size_t)b * LL;
  const float4* tb = (const float4*)(th + (size_t)b * LL * DD);

  float m = NEGI, s = 0.f;
  float4 a0 = make_float4(0.f, 0.f, 0.f, 0.f), a1 = a0, a2 = a0;

  #pragma unroll 2
  for (int l = s0 + slot; l < e0; l += SLOTS) {
    const float4* row = tb + (size_t)l * (DD / 4);
    float4 r0 = row[lane], r1 = row[lane + 64], r2 = row[lane + 128];
    float am = arow[l];  // lane-uniform broadcast load

    float d = 0.f;
    d = fmaf(r0.x, w0.x, d); d = fmaf(r0.y, w0.y, d);
    d = fmaf(r0.z, w0.z, d); d = fmaf(r0.w, w0.w, d);
    d = fmaf(r1.x, w1.x, d); d = fmaf(r1.y, w1.y, d);
    d = fmaf(r1.z, w1.z, d); d = fmaf(r1.w, w1.w, d);
    d = fmaf(r2.x, w2.x, d); d = fmaf(r2.y, w2.y, d);
    d = fmaf(r2.z, w2.z, d); d = fmaf(r2.w, w2.w, d);
    #pragma unroll
    for (int o = 32; o > 0; o >>= 1) d += __shfl_xor(d, o, 64);

    if (am >= 0.5f) {  // wave-uniform (am identical across lanes)
      const float nm = fmaxf(m, d);
      const float sc = __expf(m - nm);   // first valid row: exp(-inf)=0
      const float e  = __expf(d - nm);
      s = fmaf(s, sc, e);
      a0.x = fmaf(e, r0.x, a0.x * sc); a0.y = fmaf(e, r0.y, a0.y * sc);
      a0.z = fmaf(e, r0.z, a0.z * sc); a0.w = fmaf(e, r0.w, a0.w * sc);
      a1.x = fmaf(e, r1.x, a1.x * sc); a1.y = fmaf(e, r1.y, a1.y * sc);
      a1.z = fmaf(e, r1.z, a1.z * sc); a1.w = fmaf(e, r1.w, a1.w * sc);
      a2.x = fmaf(e, r2.x, a2.x * sc); a2.y = fmaf(e, r2.y, a2.y * sc);
      a2.z = fmaf(e, r2.z, a2.z * sc); a2.w = fmaf(e, r2.w, a2.w * sc);
      m = nm;
    }
  }

  // publish wave partials
  float4* sa = (float4*)sacc[wave];
  sa[lane] = a0; sa[lane + 64] = a1; sa[lane + 128] = a2;
  if (lane == 0) { sm[wave] = m; ss[wave] = s; }
  __syncthreads();

  // merge 4 wave-partials into one UNNORMALIZED (M, S, acc) partial.
  // Every (bk,j) writes all 770 values unconditionally — workspace is
  // poisoned between iterations, B must never read stale bytes.
  const int t = threadIdx.x;
  if (t < DD / 4) {
    float M = NEGI;
    #pragma unroll
    for (int w = 0; w < AW; ++w) M = fmaxf(M, sm[w]);
    float S = 0.f;
    float4 o = make_float4(0.f, 0.f, 0.f, 0.f);
    #pragma unroll
    for (int w = 0; w < AW; ++w) {
      const float ew = __expf(sm[w] - M);  // empty wave: s=0, acc=0 -> no-op
      S = fmaf(ew, ss[w], S);
      const float4 p = ((const float4*)sacc[w])[t];
      o.x = fmaf(ew, p.x, o.x); o.y = fmaf(ew, p.y, o.y);
      o.z = fmaf(ew, p.z, o.z); o.w = fmaf(ew, p.w, o.w);
    }
    ((float4*)(pacc + (size_t)(bk * JJ + j) * DD))[t] = o;
    if (t == 0) { pm[bk * JJ + j] = M; ps[bk * JJ + j] = S; }
  }
}

// Phase B: one 192-thread block per (b,k). Merge the J=8 partials
// (12.6 MB total read, mostly L2-warm), normalize, write H + sent.
__global__ __launch_bounds__(192) void span_pool_b(
    const float* __restrict__ pacc,
    const float* __restrict__ pm,
    const float* __restrict__ ps,
    float* __restrict__ Hout,
    float* __restrict__ sent) {
  const int bk = blockIdx.x;
  const int t = threadIdx.x;  // 0..191, one float4 of the 768 dims each

  float mj[JJ], sj[JJ];
  float M = NEGI;
  #pragma unroll
  for (int jv = 0; jv < JJ; ++jv) {
    mj[jv] = pm[bk * JJ + jv];
    sj[jv] = ps[bk * JJ + jv];
    M = fmaxf(M, mj[jv]);
  }
  float S = 0.f;
  #pragma unroll
  for (int jv = 0; jv < JJ; ++jv) S = fmaf(__expf(mj[jv] - M), sj[jv], S);
  const float inv = (S > 0.f) ? (1.0f / S) : 0.f;  // empty/all-masked -> 0

  float4 o = make_float4(0.f, 0.f, 0.f, 0.f);
  #pragma unroll
  for (int jv = 0; jv < JJ; ++jv) {
    const float ew = __expf(mj[jv] - M);  // empty partial: exp->0 or acc=0
    const float4 p = ((const float4*)(pacc + (size_t)(bk * JJ + jv) * DD))[t];
    o.x = fmaf(ew, p.x, o.x); o.y = fmaf(ew, p.y, o.y);
    o.z = fmaf(ew, p.z, o.z); o.w = fmaf(ew, p.w, o.w);
  }
  o.x *= inv; o.y *= inv; o.z *= inv; o.w *= inv;
  ((float4*)(Hout + (size_t)bk * DD))[t] = o;  // all 768 dims always written
  if (t == 0) sent[bk] = (S > 0.f) ? 1.0f : 0.0f;
}

extern "C" void kernel_launch(void* const* d_in, const int* in_sizes, int n_in,
                              void* d_out, int out_size, void* d_ws, size_t ws_size,
                              hipStream_t stream) {
  const float* th   = (const float*)d_in[0];  // [B,L,D] fp32
  const float* attn = (const float*)d_in[1];  // [B,L]   fp32
  const int*   sps  = (const int*)d_in[2];    // [B,K]
  const int*   spe  = (const int*)d_in[3];    // [B,K]
  const float* wp   = (const float*)d_in[4];  // [D]     fp32
  // d_in[5] (b_pool) intentionally unused: softmax(x + c) == softmax(x)

  float* Hout = (float*)d_out;                 // [B,K,D] then sent [B,K]
  float* sent = Hout + (size_t)BB * KK * DD;

  // workspace: 512*8*768 + 2*512*8 floats = 12.6 MB (ws is ~384 MB)
  float* pacc = (float*)d_ws;
  float* pm   = pacc + (size_t)BB * KK * JJ * DD;
  float* ps   = pm + (size_t)BB * KK * JJ;

  span_pool_a<<<dim3(BB * KK, JJ), dim3(256), 0, stream>>>(
      th, attn, sps, spe, wp, pacc, pm, ps);
  span_pool_b<<<dim3(BB * KK), dim3(192), 0, stream>>>(
      pacc, pm, ps, Hout, sent);
}